// Round 3
// baseline (67.472 us; speedup 1.0000x reference)
//
#include <hip/hip_runtime.h>

#define GSZ   64
#define G3    (GSZ * GSZ * GSZ)      // 262144
#define NCAM  8
#define NJ    23
#define IMW   1280
#define IMH   1024
#define HMW   (IMW / 2)              // 640
#define HMH   (IMH / 2)              // 512
#define HWSZ  (HMW * HMH)            // 327680

__global__ __launch_bounds__(256) void reproj_kernel(
    const float* __restrict__ hm,      // [B, C, J, 512, 640]
    const float* __restrict__ center,  // [B, 3]
    const float* __restrict__ cam,     // [B, C, 4, 3]
    float* __restrict__ out)           // [B, J, 64, 64, 64]
{
#pragma clang fp contract(off)
    const int b = blockIdx.y;

    // Wave = 4x4x4 world-space cube: minimizes the image-space bounding box
    // of the 64 lanes' projections -> fewer distinct cache lines per gather.
    const int lane = threadIdx.x & 63;
    const int wv   = threadIdx.x >> 6;
    const int q    = blockIdx.x * 4 + wv;          // cube id 0..4095
    const int qx = q >> 8, qy = (q >> 4) & 15, qz = q & 15;
    const int lx = (lane >> 4) & 3, ly = (lane >> 2) & 3, lz = lane & 3;
    const int x = (qx << 2) | lx;
    const int y = (qy << 2) | ly;
    const int z = (qz << 2) | lz;
    const int n = (x << 12) | (y << 6) | z;        // output flat index

    // stage this batch's 8 camera matrices (96 floats) in LDS
    __shared__ float sM[NCAM * 12];
    if (threadIdx.x < NCAM * 12) {
        sM[threadIdx.x] = cam[b * NCAM * 12 + threadIdx.x];
    }
    __syncthreads();

    const float cx = center[b * 3 + 0];
    const float cy = center[b * 3 + 1];
    const float cz = center[b * 3 + 2];
    const float px = (float)(x - 32) * 2.0f + cx;
    const float py = (float)(y - 32) * 2.0f + cy;
    const float pz = (float)(z - 32) * 2.0f + cz;

    float acc[NJ];
#pragma unroll
    for (int j = 0; j < NJ; ++j) acc[j] = 0.0f;

    const float* hmb = hm + (size_t)b * NCAM * NJ * HWSZ;

    for (int c = 0; c < NCAM; ++c) {
        const float* M = &sM[c * 12];   // M[k*3 + m]
        // XLA/Eigen gemm ordering: sequential FMA along ascending k.
        float p0 = fmaf(pz, M[6], fmaf(py, M[3], px * M[0])) + M[9];
        float p1 = fmaf(pz, M[7], fmaf(py, M[4], px * M[1])) + M[10];
        float p2 = fmaf(pz, M[8], fmaf(py, M[5], px * M[2])) + M[11];

        float u = p0 / p2;              // IEEE divide (no fast-math)
        float v = p1 / p2;
        u = fminf(fmaxf(u, 0.0f), (float)(IMW - 1));
        v = fminf(fmaxf(v, 0.0f), (float)(IMH - 1));
        const int idx = (int)(v * 0.5f) * HMW + (int)(u * 0.5f);

        const float* plane = hmb + (size_t)c * NJ * HWSZ + idx;
#pragma unroll
        for (int j = 0; j < NJ; ++j) {
            acc[j] += plane[(size_t)j * HWSZ];
        }
    }

    float* ob = out + (size_t)b * NJ * G3 + n;
#pragma unroll
    for (int j = 0; j < NJ; ++j) {
        ob[(size_t)j * G3] = acc[j] * 0.125f;
    }
}

extern "C" void kernel_launch(void* const* d_in, const int* in_sizes, int n_in,
                              void* d_out, int out_size, void* d_ws, size_t ws_size,
                              hipStream_t stream) {
    const float* hm     = (const float*)d_in[0];
    const float* center = (const float*)d_in[1];
    const float* cam    = (const float*)d_in[2];
    float* out          = (float*)d_out;

    dim3 grid(G3 / 64 / 4, 2, 1);   // 1024 blocks x 4 waves = 4096 cubes per batch
    dim3 block(256, 1, 1);
    reproj_kernel<<<grid, block, 0, stream>>>(hm, center, cam, out);
}

// Round 4
// 47.470 us; speedup vs baseline: 1.4214x; 1.4214x over previous
//
#include <hip/hip_runtime.h>

#define GSZ   64
#define G3    (GSZ * GSZ * GSZ)      // 262144
#define NCAM  8
#define NJ    23
#define IMW   1280
#define IMH   1024
#define HMW   (IMW / 2)              // 640
#define HMH   (IMH / 2)              // 512
#define HWSZ  (HMW * HMH)            // 327680

__global__ __launch_bounds__(256) void reproj_kernel(
    const float* __restrict__ hm,      // [B, C, J, 512, 640]
    const float* __restrict__ center,  // [B, 3]
    const float* __restrict__ cam,     // [B, C, 4, 3]
    float* __restrict__ out)           // [B, J, 64, 64, 64]
{
#pragma clang fp contract(off)
    // batch <-> XCD parity: round-robin block dispatch sends even blocks to
    // even XCDs -> each XCD's L2 caches only one batch's heatmaps.
    const int bid = blockIdx.x;
    const int b   = bid & 1;
    const int n   = (bid >> 1) * 256 + threadIdx.x;   // z-line mapping (coalesced stores)
    const int z = n & 63;
    const int y = (n >> 6) & 63;
    const int x = n >> 12;

    __shared__ float sM[NCAM * 12];
    if (threadIdx.x < NCAM * 12) {
        sM[threadIdx.x] = cam[b * NCAM * 12 + threadIdx.x];
    }
    __syncthreads();

    const float cx = center[b * 3 + 0];
    const float cy = center[b * 3 + 1];
    const float cz = center[b * 3 + 2];
    const float px = (float)(x - 32) * 2.0f + cx;
    const float py = (float)(y - 32) * 2.0f + cy;
    const float pz = (float)(z - 32) * 2.0f + cz;

    const float* __restrict__ hmb = hm + (size_t)b * NCAM * NJ * HWSZ;

    // ---- hoisted: all 8 projections -> flat element offsets ----
    int off[NCAM];
#pragma unroll
    for (int c = 0; c < NCAM; ++c) {
        const float* M = &sM[c * 12];
        // XLA/Eigen ordering: sequential FMA along ascending k (bit-exact, R2-verified)
        float p0 = fmaf(pz, M[6], fmaf(py, M[3], px * M[0])) + M[9];
        float p1 = fmaf(pz, M[7], fmaf(py, M[4], px * M[1])) + M[10];
        float p2 = fmaf(pz, M[8], fmaf(py, M[5], px * M[2])) + M[11];
        float u = p0 / p2;              // IEEE divide (no fast-math)
        float v = p1 / p2;
        u = fminf(fmaxf(u, 0.0f), (float)(IMW - 1));
        v = fminf(fmaxf(v, 0.0f), (float)(IMH - 1));
        off[c] = c * (NJ * HWSZ) + (int)(v * 0.5f) * HMW + (int)(u * 0.5f);
    }

    // ---- depth-2 software-pipelined gather over cameras ----
    float acc[NJ], bA[NJ], bB[NJ];

    auto issue = [&](float* buf, int c) {
#pragma unroll
        for (int j = 0; j < NJ; ++j) buf[j] = hmb[off[c] + j * HWSZ];
    };

    issue(bA, 0);
    issue(bB, 1);
#pragma unroll
    for (int j = 0; j < NJ; ++j) acc[j] = bA[j];       // camera-sum order is fp-free (mean), buckets already exact
    issue(bA, 2);
#pragma unroll
    for (int j = 0; j < NJ; ++j) acc[j] += bB[j];
    issue(bB, 3);
#pragma unroll
    for (int j = 0; j < NJ; ++j) acc[j] += bA[j];
    issue(bA, 4);
#pragma unroll
    for (int j = 0; j < NJ; ++j) acc[j] += bB[j];
    issue(bB, 5);
#pragma unroll
    for (int j = 0; j < NJ; ++j) acc[j] += bA[j];
    issue(bA, 6);
#pragma unroll
    for (int j = 0; j < NJ; ++j) acc[j] += bB[j];
    issue(bB, 7);
#pragma unroll
    for (int j = 0; j < NJ; ++j) acc[j] += bA[j];
#pragma unroll
    for (int j = 0; j < NJ; ++j) acc[j] += bB[j];

    float* ob = out + (size_t)b * NJ * G3 + n;
#pragma unroll
    for (int j = 0; j < NJ; ++j) {
        ob[(size_t)j * G3] = acc[j] * 0.125f;
    }
}

extern "C" void kernel_launch(void* const* d_in, const int* in_sizes, int n_in,
                              void* d_out, int out_size, void* d_ws, size_t ws_size,
                              hipStream_t stream) {
    const float* hm     = (const float*)d_in[0];
    const float* center = (const float*)d_in[1];
    const float* cam    = (const float*)d_in[2];
    float* out          = (float*)d_out;

    dim3 grid((G3 / 256) * 2, 1, 1);   // 2048 blocks: (n-chunk, batch) interleaved on bit 0
    dim3 block(256, 1, 1);
    reproj_kernel<<<grid, block, 0, stream>>>(hm, center, cam, out);
}

// Round 5
// 46.058 us; speedup vs baseline: 1.4649x; 1.0307x over previous
//
#include <hip/hip_runtime.h>

#define GSZ   64
#define G3    (GSZ * GSZ * GSZ)      // 262144
#define NCAM  8
#define NJ    23
#define IMW   1280
#define IMH   1024
#define HMW   (IMW / 2)              // 640
#define HMH   (IMH / 2)              // 512
#define HWSZ  (HMW * HMH)            // 327680

__global__ __launch_bounds__(256) void reproj_kernel(
    const float* __restrict__ hm,      // [B, C, J, 512, 640]
    const float* __restrict__ center,  // [B, 3]
    const float* __restrict__ cam,     // [B, C, 4, 3]
    float* __restrict__ out)           // [B, J, 64, 64, 64]
{
#pragma clang fp contract(off)
    const int bid = blockIdx.x;
    const int b   = bid & 1;                          // batch<->XCD parity
    const int n   = (bid >> 1) * 256 + threadIdx.x;   // z-line waves: lane == z
    const int z = n & 63;
    const int y = (n >> 6) & 63;
    const int x = n >> 12;
    const int lane = threadIdx.x & 63;

    __shared__ float sM[NCAM * 12];
    if (threadIdx.x < NCAM * 12) {
        sM[threadIdx.x] = cam[b * NCAM * 12 + threadIdx.x];
    }
    __syncthreads();

    const float cx = center[b * 3 + 0];
    const float cy = center[b * 3 + 1];
    const float cz = center[b * 3 + 2];
    const float px = (float)(x - 32) * 2.0f + cx;
    const float py = (float)(y - 32) * 2.0f + cy;
    const float pz = (float)(z - 32) * 2.0f + cz;

    const float* __restrict__ hmb = hm + (size_t)b * NCAM * NJ * HWSZ;

    // ---- hoisted projections + per-camera wave dedup (segmented leaders) ----
    int  off[NCAM];      // leader's flat element offset (cam base + pixel idx)
    int  leader[NCAM];   // lane id supplying my value
    bool isldr[NCAM];
#pragma unroll
    for (int c = 0; c < NCAM; ++c) {
        const float* M = &sM[c * 12];
        // XLA/Eigen ordering: sequential FMA along ascending k (bit-exact, R2-verified)
        float p0 = fmaf(pz, M[6], fmaf(py, M[3], px * M[0])) + M[9];
        float p1 = fmaf(pz, M[7], fmaf(py, M[4], px * M[1])) + M[10];
        float p2 = fmaf(pz, M[8], fmaf(py, M[5], px * M[2])) + M[11];
        float u = p0 / p2;              // IEEE divide (no fast-math)
        float v = p1 / p2;
        u = fminf(fmaxf(u, 0.0f), (float)(IMW - 1));
        v = fminf(fmaxf(v, 0.0f), (float)(IMH - 1));
        const int idx = (int)(v * 0.5f) * HMW + (int)(u * 0.5f);
        off[c] = c * (NJ * HWSZ) + idx;

        const int  prev  = __shfl_up(idx, 1);
        const bool start = (lane == 0) || (idx != prev);
        const unsigned long long mask = __ballot(start);
        // nearest run-start at-or-below my lane
        leader[c] = lane - __clzll(mask << (63 - lane));
        isldr[c]  = start;
    }

    // ---- depth-2 pipelined gather: leader lanes load, all lanes shfl ----
    float acc[NJ], tA[NJ], tB[NJ];

#define ISSUE(buf, c)                                                        \
    if (isldr[c]) {                                                          \
        _Pragma("unroll")                                                    \
        for (int j = 0; j < NJ; ++j) buf[j] = hmb[off[c] + j * HWSZ];        \
    }
#define CONS0(buf, c)                                                        \
    {                                                                        \
        _Pragma("unroll")                                                    \
        for (int j = 0; j < NJ; ++j) acc[j] = __shfl(buf[j], leader[c]);     \
    }
#define CONS(buf, c)                                                         \
    {                                                                        \
        _Pragma("unroll")                                                    \
        for (int j = 0; j < NJ; ++j) acc[j] += __shfl(buf[j], leader[c]);    \
    }

    ISSUE(tA, 0)
    ISSUE(tB, 1)
    CONS0(tA, 0)
    ISSUE(tA, 2)
    CONS (tB, 1)
    ISSUE(tB, 3)
    CONS (tA, 2)
    ISSUE(tA, 4)
    CONS (tB, 3)
    ISSUE(tB, 5)
    CONS (tA, 4)
    ISSUE(tA, 6)
    CONS (tB, 5)
    ISSUE(tB, 7)
    CONS (tA, 6)
    CONS (tB, 7)

#undef ISSUE
#undef CONS0
#undef CONS

    float* ob = out + (size_t)b * NJ * G3 + n;
#pragma unroll
    for (int j = 0; j < NJ; ++j) {
        ob[(size_t)j * G3] = acc[j] * 0.125f;
    }
}

extern "C" void kernel_launch(void* const* d_in, const int* in_sizes, int n_in,
                              void* d_out, int out_size, void* d_ws, size_t ws_size,
                              hipStream_t stream) {
    const float* hm     = (const float*)d_in[0];
    const float* center = (const float*)d_in[1];
    const float* cam    = (const float*)d_in[2];
    float* out          = (float*)d_out;

    dim3 grid((G3 / 256) * 2, 1, 1);   // (n-chunk, batch) interleaved on bit 0
    dim3 block(256, 1, 1);
    reproj_kernel<<<grid, block, 0, stream>>>(hm, center, cam, out);
}

// Round 6
// 42.310 us; speedup vs baseline: 1.5947x; 1.0886x over previous
//
#include <hip/hip_runtime.h>

#define GSZ   64
#define G3    (GSZ * GSZ * GSZ)      // 262144
#define NCAM  8
#define NJ    23
#define IMW   1280
#define IMH   1024
#define HMW   (IMW / 2)              // 640
#define HMH   (IMH / 2)              // 512
#define HWSZ  (HMW * HMH)            // 327680
#define RMAX  32                     // packed-path cap on distinct runs/wave
#define TMAX  ((RMAX * NJ + 63) / 64)  // 12 packed gather rounds max

__global__ __launch_bounds__(256) void reproj_kernel(
    const float* __restrict__ hm,      // [B, C, J, 512, 640]
    const float* __restrict__ center,  // [B, 3]
    const float* __restrict__ cam,     // [B, C, 4, 3]
    float* __restrict__ out)           // [B, J, 64, 64, 64]
{
#pragma clang fp contract(off)
    const int bid  = blockIdx.x;
    const int b    = bid & 1;                          // batch<->XCD parity
    const int n    = (bid >> 1) * 256 + threadIdx.x;   // z-line waves: lane == z
    const int z = n & 63;
    const int y = (n >> 6) & 63;
    const int x = n >> 12;
    const int lane = threadIdx.x & 63;
    const int wv   = threadIdx.x >> 6;

    __shared__ float sM[NCAM * 12];
    __shared__ int   sOff[4][RMAX];                    // per-wave deduped offsets
    __shared__ __align__(16) float sStage[4][RMAX * 24]; // [run][joint(+pad)]

    if (threadIdx.x < NCAM * 12) {
        sM[threadIdx.x] = cam[b * NCAM * 12 + threadIdx.x];
    }
    __syncthreads();

    const float cx = center[b * 3 + 0];
    const float cy = center[b * 3 + 1];
    const float cz = center[b * 3 + 2];
    const float px = (float)(x - 32) * 2.0f + cx;
    const float py = (float)(y - 32) * 2.0f + cy;
    const float pz = (float)(z - 32) * 2.0f + cz;

    const float* __restrict__ hmb = hm + (size_t)b * NCAM * NJ * HWSZ;

    // ---- projections + per-camera wave dedup ----
    int off[NCAM];       // my flat element offset (cam base + pixel)
    int runix[NCAM];     // my run index within the wave
    int Rcnt[NCAM];      // wave-uniform distinct-run count
    unsigned ldrbits = 0;
#pragma unroll
    for (int c = 0; c < NCAM; ++c) {
        const float* M = &sM[c * 12];
        // XLA/Eigen ordering: sequential FMA along ascending k (bit-exact, R2-verified)
        float p0 = fmaf(pz, M[6], fmaf(py, M[3], px * M[0])) + M[9];
        float p1 = fmaf(pz, M[7], fmaf(py, M[4], px * M[1])) + M[10];
        float p2 = fmaf(pz, M[8], fmaf(py, M[5], px * M[2])) + M[11];
        float u = p0 / p2;              // IEEE divide (no fast-math)
        float v = p1 / p2;
        u = fminf(fmaxf(u, 0.0f), (float)(IMW - 1));
        v = fminf(fmaxf(v, 0.0f), (float)(IMH - 1));
        const int idx = (int)(v * 0.5f) * HMW + (int)(u * 0.5f);
        off[c] = c * (NJ * HWSZ) + idx;

        const int  prev  = __shfl_up(idx, 1);
        const bool start = (lane == 0) || (idx != prev);
        const unsigned long long mask = __ballot(start);
        runix[c] = __popcll(mask & ((2ull << lane) - 1ull)) - 1;
        Rcnt[c]  = __popcll(mask);
        ldrbits |= ((unsigned)start) << c;
    }

    float acc[NJ];
#pragma unroll
    for (int j = 0; j < NJ; ++j) acc[j] = 0.0f;

#pragma unroll
    for (int c = 0; c < NCAM; ++c) {
        const int R     = Rcnt[c];
        const int myrun = runix[c];
        if (R <= RMAX) {
            // leaders publish deduped offsets (same-wave DS ops are in-order)
            if ((ldrbits >> c) & 1u) sOff[wv][myrun] = off[c];
            const int vcnt = R * NJ;

            // A1: fetch round offsets from LDS (all reads issue together)
            int po[TMAX];
#pragma unroll
            for (int t = 0; t < TMAX; ++t) {
                const int p = t * 64 + lane;
                if (p < vcnt) {
                    const int r = (int)((unsigned)p / 23u);
                    po[t] = sOff[wv][r];
                }
            }
            // A2: packed gathers — all 64 lanes fetch distinct (run,joint) values
            float val[TMAX];
#pragma unroll
            for (int t = 0; t < TMAX; ++t) {
                const int p = t * 64 + lane;
                if (p < vcnt) {
                    const int r = (int)((unsigned)p / 23u);
                    const int j = p - r * 23;
                    val[t] = hmb[po[t] + j * HWSZ];
                }
            }
            // B: stage into LDS [run][joint]
#pragma unroll
            for (int t = 0; t < TMAX; ++t) {
                const int p = t * 64 + lane;
                if (p < vcnt) {
                    const int r = (int)((unsigned)p / 23u);
                    const int j = p - r * 23;
                    sStage[wv][r * 24 + j] = val[t];
                }
            }
            // C: vectorized read-back of my run's 23 joints
            const float4* s4 = (const float4*)&sStage[wv][myrun * 24];
            const float4 a0 = s4[0], a1 = s4[1], a2 = s4[2], a3 = s4[3], a4 = s4[4];
            const float2 a5 = *(const float2*)&sStage[wv][myrun * 24 + 20];
            const float  a6 = sStage[wv][myrun * 24 + 22];
            acc[ 0] += a0.x; acc[ 1] += a0.y; acc[ 2] += a0.z; acc[ 3] += a0.w;
            acc[ 4] += a1.x; acc[ 5] += a1.y; acc[ 6] += a1.z; acc[ 7] += a1.w;
            acc[ 8] += a2.x; acc[ 9] += a2.y; acc[10] += a2.z; acc[11] += a2.w;
            acc[12] += a3.x; acc[13] += a3.y; acc[14] += a3.z; acc[15] += a3.w;
            acc[16] += a4.x; acc[17] += a4.y; acc[18] += a4.z; acc[19] += a4.w;
            acc[20] += a5.x; acc[21] += a5.y; acc[22] += a6;
        } else {
            // rare high-diversity wave: plain per-lane gather
            const int o = off[c];
#pragma unroll
            for (int j = 0; j < NJ; ++j) acc[j] += hmb[o + j * HWSZ];
        }
    }

    float* ob = out + (size_t)b * NJ * G3 + n;
#pragma unroll
    for (int j = 0; j < NJ; ++j) {
        ob[(size_t)j * G3] = acc[j] * 0.125f;
    }
}

extern "C" void kernel_launch(void* const* d_in, const int* in_sizes, int n_in,
                              void* d_out, int out_size, void* d_ws, size_t ws_size,
                              hipStream_t stream) {
    const float* hm     = (const float*)d_in[0];
    const float* center = (const float*)d_in[1];
    const float* cam    = (const float*)d_in[2];
    float* out          = (float*)d_out;

    dim3 grid((G3 / 256) * 2, 1, 1);   // (n-chunk, batch) interleaved on bit 0
    dim3 block(256, 1, 1);
    reproj_kernel<<<grid, block, 0, stream>>>(hm, center, cam, out);
}